// Round 12
// baseline (776.259 us; speedup 1.0000x reference)
//
#include <hip/hip_runtime.h>

// ScaledDotProductAttention: B=2,H=16,S=2048,DK=DV=64, fp32 in/out, mask (True => -1e9).
// R19 = R18 resubmission (broker timeout; never measured). Wave-split structure
//       (q-half x key-half: 32q x 32k per wave, halves per-wave LDS reads to
//       8 b128/iter at unchanged 16 waves/CU) with BOTH R15 failure modes fixed:
//   (1) bank collapse: K staging swizzle gains row-bit3, cswK = csw ^ ((w&1)<<2), and
//       ka reads add kx = ((c>>2)&1)<<2 -> 8 chunk-slots x 8 lanes (distinct rows),
//       all 32 banks covered (R15 funneled 16 lanes into 4 slots = half banks).
//   (2) VGPR pressure (R15 peak ~130 > 128 cap): tight liveness -- ka read+consumed
//       per kt then dead; ONE vb per dt shared by both qg's PV MFMAs; peak ~90-110.
//   Measured ladder: R8 757.8 / R12 781 / R13 776 / R15 787 / R17 751.5 (best).
//   Theory: attn ~75us is LDS-pipe-bound (~34us reads+writes/CU); this halves read
//   bytes per unit work -> predict dur ~735-742.

#define LOG2E 1.4426950408889634f
#define QSCALE (0.125f * LOG2E)          // fold 1/sqrt(64) and log2(e) into Q

typedef __attribute__((ext_vector_type(8))) short short8;   // 8 x bf16
typedef __attribute__((ext_vector_type(4))) short short4v;  // 4 x bf16
typedef __attribute__((ext_vector_type(4))) float f32x4;    // MFMA acc
typedef unsigned __attribute__((ext_vector_type(4))) uintv4;

constexpr int S = 2048, D = 64;

__device__ __forceinline__ short bf16rne(float x) {
  union { float f; unsigned u; } cv; cv.f = x;
  unsigned u = cv.u;
  u += 0x7fffu + ((u >> 16) & 1u);
  return (short)(u >> 16);
}

__device__ __forceinline__ void glds16(const void* g, void* l) {
  __builtin_amdgcn_global_load_lds(
      (const __attribute__((address_space(1))) void*)g,
      (__attribute__((address_space(3))) void*)l, 16, 0, 0);
}

// Merged prep: blocks [0,2048) convert K fp32->bf16; [2048,3072) build bf16 V^T.
// Block 0 wave 0 additionally detects mask format: 1 = byte-packed, 0 = 4-byte elems.
__global__ void prep(const float* __restrict__ kp, const float* __restrict__ vp,
                     short* __restrict__ kb, short* __restrict__ vt,
                     const unsigned* __restrict__ m, int* __restrict__ flag) {
  const int b = blockIdx.x;
  const int tid = threadIdx.x;
  if (b == 0 && tid < 64) {
    unsigned v = m[tid];
    unsigned long long big = __ballot(v > 1u && v != 0x3F800000u);
    unsigned long long isf = __ballot(v == 0x3F800000u);
    if (tid == 0) *flag = (big != 0ull && isf == 0ull) ? 1 : 0;
  }
  if (b < 2048) {
    size_t i = ((size_t)b * 256 + tid) * 8;
    float4 a = *(const float4*)(kp + i);
    float4 c = *(const float4*)(kp + i + 4);
    short8 s;
    s[0] = bf16rne(a.x); s[1] = bf16rne(a.y); s[2] = bf16rne(a.z); s[3] = bf16rne(a.w);
    s[4] = bf16rne(c.x); s[5] = bf16rne(c.y); s[6] = bf16rne(c.z); s[7] = bf16rne(c.w);
    *(short8*)&kb[i] = s;
  } else {
    __shared__ float tile[64][65];
    const int bb = b - 2048;
    const int bh = bb >> 5, k0 = (bb & 31) * 64;
    const float* src = vp + ((size_t)(bh * S + k0)) * D;
#pragma unroll
    for (int i = 0; i < 4; ++i) {
      int row = i * 16 + (tid >> 4);
      int col = (tid & 15) * 4;
      float4 x = *(const float4*)(src + row * D + col);
      tile[row][col] = x.x; tile[row][col + 1] = x.y;
      tile[row][col + 2] = x.z; tile[row][col + 3] = x.w;
    }
    __syncthreads();
#pragma unroll
    for (int i = 0; i < 4; ++i) {
      int dim = i * 16 + (tid >> 4);
      int kb4 = (tid & 15) * 4;
      short4v s;
#pragma unroll
      for (int j = 0; j < 4; ++j) s[j] = bf16rne(tile[kb4 + j][dim]);
      *(short4v*)&vt[((size_t)(bh * D + dim)) * S + k0 + kb4] = s;
    }
  }
}

__launch_bounds__(256, 4)
__global__ void attn_fwd(const float* __restrict__ qp, const short* __restrict__ kb,
                         const short* __restrict__ vt, const void* __restrict__ mp,
                         float* __restrict__ op, const int* __restrict__ fmtp) {
  const int fmt  = *fmtp;
  const int tid  = threadIdx.x;
  const int lane = tid & 63;
  const int w    = tid >> 6;          // wave 0..3
  const int c    = lane & 15;
  const int quad = lane >> 4;
  const int kh   = w & 1;             // key-half: this wave's 32 keys of the 64-key tile
  const int qh   = w >> 1;            // q-half:   this wave's 32 q-rows of the 64-q block

  const int bh = blockIdx.x >> 5;
  const int q0 = (blockIdx.x & 31) * 64;

  // 32 KiB: K tile dbuf + V^T tile dbuf. Epilogue scratch aliases this block.
  __shared__ __align__(16) char smem[32768];
  short* ksb = (short*)smem;                    // [2][64*64] K  [key][dim]
  short* vsb = (short*)(smem + 16384);          // [2][64*64] V^T [dim][key]
  float* Osc = (float*)smem;                    // epilogue: [64][66] partial O
  float* Lsc = (float*)(smem + 17000);          // epilogue: [64] partial L

  // ---- Q B-fragments: qB[qg][kk] = Q[q0+qh*32+qg*16+c][kk*32+quad*8 ..+7] ----
  short8 qB[2][2];
#pragma unroll
  for (int qg = 0; qg < 2; ++qg) {
    const float* qg_p = qp + ((size_t)(bh * S + q0 + qh * 32 + qg * 16 + c)) * D;
#pragma unroll
    for (int kk = 0; kk < 2; ++kk) {
      const float* p = qg_p + kk * 32 + quad * 8;
      float4 x = *(const float4*)(p);
      float4 y = *(const float4*)(p + 4);
      short8 f;
      f[0] = bf16rne(x.x * QSCALE); f[1] = bf16rne(x.y * QSCALE);
      f[2] = bf16rne(x.z * QSCALE); f[3] = bf16rne(x.w * QSCALE);
      f[4] = bf16rne(y.x * QSCALE); f[5] = bf16rne(y.y * QSCALE);
      f[6] = bf16rne(y.z * QSCALE); f[7] = bf16rne(y.w * QSCALE);
      qB[qg][kk] = f;
    }
  }

  f32x4 O[2][4];
#pragma unroll
  for (int qg = 0; qg < 2; ++qg)
#pragma unroll
    for (int dt = 0; dt < 4; ++dt) O[qg][dt] = (f32x4){0.f, 0.f, 0.f, 0.f};
  float Lp[2] = {0.f, 0.f};

  // staging geometry (R8/R17): slot=(h2*4+w)*8+rsub rows; K gets row-bit3 spread.
  const int rsub = lane >> 3;
  const int cswV = (lane & 7) ^ rsub;                 // V swizzle (R8)
  const int cswK = cswV ^ ((w & 1) << 2);             // K swizzle (R17-validated)
  const short* kbase = kb + ((size_t)(bh * S)) * D;
  const short* vbase = vt + ((size_t)(bh * D)) * S;

  const int kx = (((c >> 2) & 1) << 2);               // K-read row-bit3 term

  const size_t mro0 = ((size_t)(bh * S + q0 + qh * 32 + c)) * S;  // qg=0 row (elems)
  const size_t mro1 = mro0 + (size_t)16 * S;                      // qg=1 row

  unsigned long long mm[2];           // mask prefetch regs [qg]

  auto stage = [&](int it, int buf) {
    const int k0 = it * 64;
#pragma unroll
    for (int h2 = 0; h2 < 2; ++h2) {
      const int row = (h2 * 4 + w) * 8 + rsub;
      glds16(kbase + (size_t)(k0 + row) * 64 + cswK * 8,
             (char*)&ksb[buf * 4096] + (h2 * 4 + w) * 1024);
      glds16(vbase + (size_t)row * S + k0 + cswV * 8,
             (char*)&vsb[buf * 4096] + (h2 * 4 + w) * 1024);
    }
  };

  auto mload = [&](int it) {
    const int kO = it * 64 + kh * 32;
    if (fmt == 1) {
#pragma unroll
      for (int qg = 0; qg < 2; ++qg)
        mm[qg] = __builtin_nontemporal_load((const unsigned long long*)
            ((const unsigned char*)mp + (qg ? mro1 : mro0) + kO + 8 * quad));
    } else {
#pragma unroll
      for (int qg = 0; qg < 2; ++qg) {
        const unsigned* m0 = (const unsigned*)mp + (qg ? mro1 : mro0) + kO + 8 * quad;
        uintv4 a = __builtin_nontemporal_load((const uintv4*)m0);
        uintv4 b = __builtin_nontemporal_load((const uintv4*)(m0 + 4));
        unsigned long long t = 0ull;
#pragma unroll
        for (int j = 0; j < 4; ++j) {
          if (a[j]) t |= 0xffull << (8 * j);
          if (b[j]) t |= 0xffull << (8 * (j + 4));
        }
        mm[qg] = t;
      }
    }
  };

  // ---- prologue ----
  stage(0, 0);
  mload(0);

  for (int it = 0; it < 32; ++it) {
    const int buf = it & 1;
    // ONE barrier/iter (R8-verified): drains glds(it)+mask(it), orders prev-iter
    // LDS reads before the buf^1 writes issued next.
    __syncthreads();

    if (it + 1 < 32) stage(it + 1, buf ^ 1);

    const unsigned long long mb0 = mm[0], mb1 = mm[1];
    if (it + 1 < 32) mload(it + 1);

    // ---- scores, permuted A-rows, tight liveness: per kt {2 reads, 4 MFMA, exp} ----
    // A-row m holds key kh*32 + 8*(m>>2) + (m&3) + 4*kt
    //  => lane(quad,c) reg r = S^T[key kh*32+8*quad+4*kt+r][q=qg*16+c]
    short8 pf0, pf1;
    float part0 = 0.f, part1 = 0.f;
#pragma unroll
    for (int kt = 0; kt < 2; ++kt) {
      const int r7 = (c & 3) + 4 * kt;                // rr & 7
      const int rr = kh * 32 + 8 * (c >> 2) + r7;
      const int px = (quad ^ r7 ^ kx) * 8;            // chunk pos for dims 8*quad..
      short8 ka0 = *(const short8*)&ksb[buf * 4096 + rr * 64 + px];
      short8 ka1 = *(const short8*)&ksb[buf * 4096 + rr * 64 + (px ^ 32)];
      f32x4 z0 = (f32x4){0.f, 0.f, 0.f, 0.f};
      f32x4 z1 = (f32x4){0.f, 0.f, 0.f, 0.f};
      z0 = __builtin_amdgcn_mfma_f32_16x16x32_bf16(ka0, qB[0][0], z0, 0, 0, 0);
      z0 = __builtin_amdgcn_mfma_f32_16x16x32_bf16(ka1, qB[0][1], z0, 0, 0, 0);
      z1 = __builtin_amdgcn_mfma_f32_16x16x32_bf16(ka0, qB[1][0], z1, 0, 0, 0);
      z1 = __builtin_amdgcn_mfma_f32_16x16x32_bf16(ka1, qB[1][1], z1, 0, 0, 0);
#pragma unroll
      for (int r = 0; r < 4; ++r) {
        const int j = 4 * kt + r;
        float e0 = ((mb0 >> (8 * j)) & 0xffull) ? 0.f : exp2f(z0[r]);
        float e1 = ((mb1 >> (8 * j)) & 0xffull) ? 0.f : exp2f(z1[r]);
        part0 += e0; part1 += e1;
        pf0[j] = bf16rne(e0); pf1[j] = bf16rne(e1);
      }
    }
    Lp[0] += part0; Lp[1] += part1;

    // ---- O += P*V: one vb per dt shared by both qg (4 reads, 8 MFMA) ----
#pragma unroll
    for (int dt = 0; dt < 4; ++dt) {
      short8 vb = *(const short8*)&vsb[buf * 4096 + (dt * 16 + c) * 64 +
                                       (((kh * 4 + quad) ^ (c & 7)) * 8)];
      O[0][dt] = __builtin_amdgcn_mfma_f32_16x16x32_bf16(pf0, vb, O[0][dt], 0, 0, 0);
      O[1][dt] = __builtin_amdgcn_mfma_f32_16x16x32_bf16(pf1, vb, O[1][dt], 0, 0, 0);
    }
  }

  // ---- epilogue: reduce the two key-halves (R12-verified structure) ----
  float Lq[2];
#pragma unroll
  for (int qg = 0; qg < 2; ++qg) {
    float t = Lp[qg];
    t += __shfl_xor(t, 16);
    t += __shfl_xor(t, 32);
    Lq[qg] = t;                       // all lanes: this half's sum for q=qg*16+c
  }

  __syncthreads();                    // all tile reads done; safe to alias smem
  if (kh == 1) {
#pragma unroll
    for (int qg = 0; qg < 2; ++qg) {
#pragma unroll
      for (int dt = 0; dt < 4; ++dt)
#pragma unroll
        for (int r = 0; r < 4; ++r)
          Osc[(qh * 32 + qg * 16 + quad * 4 + r) * 66 + dt * 16 + c] = O[qg][dt][r];
    }
    if (quad == 0) {
      Lsc[qh * 32 + c]      = Lq[0];
      Lsc[qh * 32 + 16 + c] = Lq[1];
    }
  }
  __syncthreads();
  if (kh == 0) {
#pragma unroll
    for (int qg = 0; qg < 2; ++qg)
#pragma unroll
      for (int r = 0; r < 4; ++r) {
        const int qrow = qg * 16 + quad * 4 + r;
        float Ls = __shfl(Lq[qg], (lane & 48) | (quad * 4 + r)) + Lsc[qh * 32 + qrow];
        float inv = 1.f / Ls;
        const size_t ob = ((size_t)(bh * S + q0 + qh * 32 + qrow)) * D;
#pragma unroll
        for (int dt = 0; dt < 4; ++dt)
          op[ob + dt * 16 + c] =
              (O[qg][dt][r] + Osc[(qh * 32 + qrow) * 66 + dt * 16 + c]) * inv;
      }
  }
}

extern "C" void kernel_launch(void* const* d_in, const int* in_sizes, int n_in,
                              void* d_out, int out_size, void* d_ws, size_t ws_size,
                              hipStream_t stream) {
  const float* q = (const float*)d_in[0];
  const float* k = (const float*)d_in[1];
  const float* v = (const float*)d_in[2];
  const void*  m = d_in[3];

  short* kbuf = (short*)d_ws;                         // 8 MiB bf16 K
  short* vtb  = (short*)((char*)d_ws + (8u << 20));   // 8 MiB bf16 V^T
  int* flag   = (int*)((char*)d_ws + (16u << 20));

  prep<<<3072, 256, 0, stream>>>(k, v, kbuf, vtb, (const unsigned*)m, flag);
  attn_fwd<<<1024, 256, 0, stream>>>(q, kbuf, vtb, m, (float*)d_out, flag);
}

// Round 13
// 749.166 us; speedup vs baseline: 1.0362x; 1.0362x over previous
//
#include <hip/hip_runtime.h>

// ScaledDotProductAttention: B=2,H=16,S=2048,DK=DV=64, fp32 in/out, mask (True => -1e9).
// R20 = R17 (measured best: 751.5us) + ONE change: s_setprio(1) around the per-iter
//       compute cluster (scores g-loop + PV), setprio(0) before the barrier.
//   T5 mechanism (learn_hip m191: +4-7% attn): CU scheduler favors MFMA-issuing waves
//   over waves issuing glds/mask loads; our 16 waves/CU run phase-independently.
//   Wave-split family RETIRED: R13=776, R15=787, R19=776 (bank-fixed, VGPR-fixed) all
//   ~25us worse than R8-shell family (R8=757.8, R17=751.5). Halving LDS reads hurt 3x
//   -> loop is ILP/latency-bound, not LDS-throughput-bound. R17's 4 independent
//   {2 ds_read -> 2 MFMA -> 4 exp} chains per iter are the winning structure.

#define LOG2E 1.4426950408889634f
#define QSCALE (0.125f * LOG2E)          // fold 1/sqrt(64) and log2(e) into Q

typedef __attribute__((ext_vector_type(8))) short short8;   // 8 x bf16
typedef __attribute__((ext_vector_type(4))) short short4v;  // 4 x bf16
typedef __attribute__((ext_vector_type(4))) float f32x4;    // MFMA acc
typedef unsigned __attribute__((ext_vector_type(4))) uintv4;

constexpr int S = 2048, D = 64;

__device__ __forceinline__ short bf16rne(float x) {
  union { float f; unsigned u; } cv; cv.f = x;
  unsigned u = cv.u;
  u += 0x7fffu + ((u >> 16) & 1u);
  return (short)(u >> 16);
}

__device__ __forceinline__ void glds16(const void* g, void* l) {
  __builtin_amdgcn_global_load_lds(
      (const __attribute__((address_space(1))) void*)g,
      (__attribute__((address_space(3))) void*)l, 16, 0, 0);
}

// Merged prep: blocks [0,2048) convert K fp32->bf16; [2048,3072) build bf16 V^T.
// Block 0 wave 0 additionally detects mask format: 1 = byte-packed, 0 = 4-byte elems.
__global__ void prep(const float* __restrict__ kp, const float* __restrict__ vp,
                     short* __restrict__ kb, short* __restrict__ vt,
                     const unsigned* __restrict__ m, int* __restrict__ flag) {
  const int b = blockIdx.x;
  const int tid = threadIdx.x;
  if (b == 0 && tid < 64) {
    unsigned v = m[tid];
    unsigned long long big = __ballot(v > 1u && v != 0x3F800000u);
    unsigned long long isf = __ballot(v == 0x3F800000u);
    if (tid == 0) *flag = (big != 0ull && isf == 0ull) ? 1 : 0;
  }
  if (b < 2048) {
    size_t i = ((size_t)b * 256 + tid) * 8;
    float4 a = *(const float4*)(kp + i);
    float4 c = *(const float4*)(kp + i + 4);
    short8 s;
    s[0] = bf16rne(a.x); s[1] = bf16rne(a.y); s[2] = bf16rne(a.z); s[3] = bf16rne(a.w);
    s[4] = bf16rne(c.x); s[5] = bf16rne(c.y); s[6] = bf16rne(c.z); s[7] = bf16rne(c.w);
    *(short8*)&kb[i] = s;
  } else {
    __shared__ float tile[64][65];
    const int bb = b - 2048;
    const int bh = bb >> 5, k0 = (bb & 31) * 64;
    const float* src = vp + ((size_t)(bh * S + k0)) * D;
#pragma unroll
    for (int i = 0; i < 4; ++i) {
      int row = i * 16 + (tid >> 4);
      int col = (tid & 15) * 4;
      float4 x = *(const float4*)(src + row * D + col);
      tile[row][col] = x.x; tile[row][col + 1] = x.y;
      tile[row][col + 2] = x.z; tile[row][col + 3] = x.w;
    }
    __syncthreads();
#pragma unroll
    for (int i = 0; i < 4; ++i) {
      int dim = i * 16 + (tid >> 4);
      int kb4 = (tid & 15) * 4;
      short4v s;
#pragma unroll
      for (int j = 0; j < 4; ++j) s[j] = bf16rne(tile[kb4 + j][dim]);
      *(short4v*)&vt[((size_t)(bh * D + dim)) * S + k0 + kb4] = s;
    }
  }
}

__launch_bounds__(256, 4)
__global__ void attn_fwd(const float* __restrict__ qp, const short* __restrict__ kb,
                         const short* __restrict__ vt, const void* __restrict__ mp,
                         float* __restrict__ op, const int* __restrict__ fmtp) {
  const int fmt  = *fmtp;
  const int tid  = threadIdx.x;
  const int lane = tid & 63;
  const int w    = tid >> 6;          // wave 0..3
  const int c    = lane & 15;
  const int quad = lane >> 4;

  const int bh = blockIdx.x >> 5;
  const int q0 = (blockIdx.x & 31) * 64;

  __shared__ short ks[2][64 * 64];    // K tile [key][dim], swz: pos p row r holds
                                      //   global chunk p ^ (r&7) ^ (((r>>3)&1)<<2)
  __shared__ short vs[2][64 * 64];    // V^T tile [dim][key], swz: p ^ (r&7) (R8)

  // ---- Q B-fragments: lane n=c is q-row q0+w*16+c ----
  const float* qg = qp + ((size_t)(bh * S + q0 + w * 16 + c)) * D;
  short8 qB[2];
#pragma unroll
  for (int kk = 0; kk < 2; ++kk) {
    const float* p = qg + kk * 32 + quad * 8;
    float4 x = *(const float4*)(p);
    float4 y = *(const float4*)(p + 4);
    short8 f;
    f[0] = bf16rne(x.x * QSCALE); f[1] = bf16rne(x.y * QSCALE);
    f[2] = bf16rne(x.z * QSCALE); f[3] = bf16rne(x.w * QSCALE);
    f[4] = bf16rne(y.x * QSCALE); f[5] = bf16rne(y.y * QSCALE);
    f[6] = bf16rne(y.z * QSCALE); f[7] = bf16rne(y.w * QSCALE);
    qB[kk] = f;
  }

  f32x4 O[4];
#pragma unroll
  for (int t = 0; t < 4; ++t) O[t] = (f32x4){0.f, 0.f, 0.f, 0.f};
  float L = 0.f;

  // staging geometry (R8): slot=(h2*4+w)*64+lane; row=(h2*4+w)*8+(lane>>3)
  const int rsub = lane >> 3;
  const int cswV = (lane & 7) ^ rsub;                 // V swizzle (R8)
  const int cswK = cswV ^ ((w & 1) << 2);             // K swizzle: row-bit3 spread (R17)
  const short* kbase = kb + ((size_t)(bh * S)) * D;
  const short* vbase = vt + ((size_t)(bh * D)) * S;

  const int sw0 = ((quad    ) ^ (c & 7)) * 8;         // V-read positions (R8)
  const int sw1 = ((quad | 4) ^ (c & 7)) * 8;
  const int kx  = (((c >> 2) & 1) << 2);              // K-read row-bit3 term

  const size_t mrow = ((size_t)(bh * S + q0 + w * 16 + c)) * S;

  unsigned long long mm0, mm1;        // mask prefetch: keys 8q..+7 / 32+8q..+7

  auto stage = [&](int it, int buf) {
    const int k0 = it * 64;
#pragma unroll
    for (int h2 = 0; h2 < 2; ++h2) {
      const int row = (h2 * 4 + w) * 8 + rsub;
      glds16(kbase + (size_t)(k0 + row) * 64 + cswK * 8,
             (char*)&ks[buf][0] + (h2 * 4 + w) * 1024);
      glds16(vbase + (size_t)row * S + k0 + cswV * 8,
             (char*)&vs[buf][0] + (h2 * 4 + w) * 1024);
    }
  };

  auto mload = [&](int it) {
    const int kO = it * 64;
    if (fmt == 1) {
      const unsigned char* mq = (const unsigned char*)mp + mrow + kO + 8 * quad;
      mm0 = __builtin_nontemporal_load((const unsigned long long*)mq);
      mm1 = __builtin_nontemporal_load((const unsigned long long*)(mq + 32));
    } else {
#pragma unroll
      for (int h = 0; h < 2; ++h) {
        const unsigned* m0 = (const unsigned*)mp + mrow + kO + h * 32 + 8 * quad;
        uintv4 a = __builtin_nontemporal_load((const uintv4*)m0);
        uintv4 b = __builtin_nontemporal_load((const uintv4*)(m0 + 4));
        unsigned long long t = 0ull;
#pragma unroll
        for (int j = 0; j < 4; ++j) {
          if (a[j]) t |= 0xffull << (8 * j);
          if (b[j]) t |= 0xffull << (8 * (j + 4));
        }
        if (h == 0) mm0 = t; else mm1 = t;
      }
    }
  };

  // ---- prologue ----
  stage(0, 0);
  mload(0);

  for (int it = 0; it < 32; ++it) {
    const int buf = it & 1;
    // ONE barrier/iter (R8): drains glds(it)+mask(it), orders prev-iter LDS reads
    // before the buf^1 writes issued next.
    __syncthreads();

    if (it + 1 < 32) stage(it + 1, buf ^ 1);

    const unsigned long long mb0 = mm0, mb1 = mm1;
    if (it + 1 < 32) mload(it + 1);

    // ---- compute cluster under raised priority (T5) ----
    __builtin_amdgcn_s_setprio(1);

    // scores, permuted A-rows; build PV A-fragments pa0/pa1 in registers (R17)
    // g: A-row m holds key 32*(g>=2) + 8*(m>>2) + 4*(g&1) + (m&3)
    //  => lane(quad,c) reg r = S^T[key 32*(g>=2)+8*quad+4*(g&1)+r][q=c]
    short8 pa0, pa1;
    float part = 0.f;
#pragma unroll
    for (int g = 0; g < 4; ++g) {
      const int r7 = (c & 3) + 4 * (g & 1);           // rr & 7
      const int rr = ((g & 2) << 4) + 8 * (c >> 2) + r7;
      const int px = ((quad ^ r7 ^ kx)) * 8;          // chunk pos for dims 8*quad..
      short8 ka0 = *(const short8*)&ks[buf][rr * 64 + px];
      short8 ka1 = *(const short8*)&ks[buf][rr * 64 + (px ^ 32)];  // dims 32+8*quad..
      f32x4 z = (f32x4){0.f, 0.f, 0.f, 0.f};
      z = __builtin_amdgcn_mfma_f32_16x16x32_bf16(ka0, qB[0], z, 0, 0, 0);
      z = __builtin_amdgcn_mfma_f32_16x16x32_bf16(ka1, qB[1], z, 0, 0, 0);
      const unsigned long long mq = (g & 2) ? mb1 : mb0;
#pragma unroll
      for (int r = 0; r < 4; ++r) {
        const int j = 4 * (g & 1) + r;
        float e = ((mq >> (8 * j)) & 0xffull) ? 0.f : exp2f(z[r]);
        part += e;
        if (g & 2) pa1[j] = bf16rne(e); else pa0[j] = bf16rne(e);
      }
    }

    part += __shfl_xor(part, 16);
    part += __shfl_xor(part, 32);
    L += part;

    // O += P*V (pa register-direct; V reads = R8 pattern)
#pragma unroll
    for (int t = 0; t < 4; ++t) {
      short8 vb0 = *(const short8*)&vs[buf][(16 * t + c) * 64 + sw0];
      short8 vb1 = *(const short8*)&vs[buf][(16 * t + c) * 64 + sw1];
      O[t] = __builtin_amdgcn_mfma_f32_16x16x32_bf16(pa0, vb0, O[t], 0, 0, 0);
      O[t] = __builtin_amdgcn_mfma_f32_16x16x32_bf16(pa1, vb1, O[t], 0, 0, 0);
    }

    __builtin_amdgcn_s_setprio(0);
  }

  // ---- epilogue: O[m=q=quad*4+r][n=dim=16t+c] / L(q) (R8) ----
#pragma unroll
  for (int r = 0; r < 4; ++r) {
    float Lr = __shfl(L, (lane & 48) | (quad * 4 + r));
    float inv = 1.f / Lr;
    const size_t ob = ((size_t)(bh * S + q0 + w * 16 + quad * 4 + r)) * D;
#pragma unroll
    for (int t = 0; t < 4; ++t) op[ob + 16 * t + c] = O[t][r] * inv;
  }
}

extern "C" void kernel_launch(void* const* d_in, const int* in_sizes, int n_in,
                              void* d_out, int out_size, void* d_ws, size_t ws_size,
                              hipStream_t stream) {
  const float* q = (const float*)d_in[0];
  const float* k = (const float*)d_in[1];
  const float* v = (const float*)d_in[2];
  const void*  m = d_in[3];

  short* kbuf = (short*)d_ws;                         // 8 MiB bf16 K
  short* vtb  = (short*)((char*)d_ws + (8u << 20));   // 8 MiB bf16 V^T
  int* flag   = (int*)((char*)d_ws + (16u << 20));

  prep<<<3072, 256, 0, stream>>>(k, v, kbuf, vtb, (const unsigned*)m, flag);
  attn_fwd<<<1024, 256, 0, stream>>>(q, kbuf, vtb, m, (float*)d_out, flag);
}

// Round 14
// 747.194 us; speedup vs baseline: 1.0389x; 1.0026x over previous
//
#include <hip/hip_runtime.h>

// ScaledDotProductAttention: B=2,H=16,S=2048,DK=DV=64, fp32 in/out, mask (True => -1e9).
// R21 = R20 (measured best: 749.2us = R17 + setprio) + op-thinning bundle (all
//       numerics-safe; bundled because each alone is sub-noise):
//   (1) L quad-reduction (2x shfl_xor + adds per iter) deferred to epilogue --
//       lane-local accumulation, one reduction after the loop. -64 DS ops/wave.
//   (2) L accumulated in 4 independent chains Lv[r] (was a 16-deep serial fadd
//       chain per iter + per-iter collapse). Latency + ~3 adds/iter.
//   (3) mask tests on u32 halves (v_bfe_u32 single-op extract) instead of 64-bit
//       shifts. ~2 ops saved x 16 tests/iter.
//   Ladder: R8 757.8 / R17 751.5 / R20 749.2 (best). Wave-split family retired
//   (R13/15/19 = 776-787: loop is ILP-bound, not LDS-throughput-bound).
//   Pre-commit: >=748.5 => bundle is noise => practical plateau; declare roofline.

#define LOG2E 1.4426950408889634f
#define QSCALE (0.125f * LOG2E)          // fold 1/sqrt(64) and log2(e) into Q

typedef __attribute__((ext_vector_type(8))) short short8;   // 8 x bf16
typedef __attribute__((ext_vector_type(4))) short short4v;  // 4 x bf16
typedef __attribute__((ext_vector_type(4))) float f32x4;    // MFMA acc
typedef unsigned __attribute__((ext_vector_type(4))) uintv4;

constexpr int S = 2048, D = 64;

__device__ __forceinline__ short bf16rne(float x) {
  union { float f; unsigned u; } cv; cv.f = x;
  unsigned u = cv.u;
  u += 0x7fffu + ((u >> 16) & 1u);
  return (short)(u >> 16);
}

__device__ __forceinline__ void glds16(const void* g, void* l) {
  __builtin_amdgcn_global_load_lds(
      (const __attribute__((address_space(1))) void*)g,
      (__attribute__((address_space(3))) void*)l, 16, 0, 0);
}

// Merged prep: blocks [0,2048) convert K fp32->bf16; [2048,3072) build bf16 V^T.
// Block 0 wave 0 additionally detects mask format: 1 = byte-packed, 0 = 4-byte elems.
__global__ void prep(const float* __restrict__ kp, const float* __restrict__ vp,
                     short* __restrict__ kb, short* __restrict__ vt,
                     const unsigned* __restrict__ m, int* __restrict__ flag) {
  const int b = blockIdx.x;
  const int tid = threadIdx.x;
  if (b == 0 && tid < 64) {
    unsigned v = m[tid];
    unsigned long long big = __ballot(v > 1u && v != 0x3F800000u);
    unsigned long long isf = __ballot(v == 0x3F800000u);
    if (tid == 0) *flag = (big != 0ull && isf == 0ull) ? 1 : 0;
  }
  if (b < 2048) {
    size_t i = ((size_t)b * 256 + tid) * 8;
    float4 a = *(const float4*)(kp + i);
    float4 c = *(const float4*)(kp + i + 4);
    short8 s;
    s[0] = bf16rne(a.x); s[1] = bf16rne(a.y); s[2] = bf16rne(a.z); s[3] = bf16rne(a.w);
    s[4] = bf16rne(c.x); s[5] = bf16rne(c.y); s[6] = bf16rne(c.z); s[7] = bf16rne(c.w);
    *(short8*)&kb[i] = s;
  } else {
    __shared__ float tile[64][65];
    const int bb = b - 2048;
    const int bh = bb >> 5, k0 = (bb & 31) * 64;
    const float* src = vp + ((size_t)(bh * S + k0)) * D;
#pragma unroll
    for (int i = 0; i < 4; ++i) {
      int row = i * 16 + (tid >> 4);
      int col = (tid & 15) * 4;
      float4 x = *(const float4*)(src + row * D + col);
      tile[row][col] = x.x; tile[row][col + 1] = x.y;
      tile[row][col + 2] = x.z; tile[row][col + 3] = x.w;
    }
    __syncthreads();
#pragma unroll
    for (int i = 0; i < 4; ++i) {
      int dim = i * 16 + (tid >> 4);
      int kb4 = (tid & 15) * 4;
      short4v s;
#pragma unroll
      for (int j = 0; j < 4; ++j) s[j] = bf16rne(tile[kb4 + j][dim]);
      *(short4v*)&vt[((size_t)(bh * D + dim)) * S + k0 + kb4] = s;
    }
  }
}

__launch_bounds__(256, 4)
__global__ void attn_fwd(const float* __restrict__ qp, const short* __restrict__ kb,
                         const short* __restrict__ vt, const void* __restrict__ mp,
                         float* __restrict__ op, const int* __restrict__ fmtp) {
  const int fmt  = *fmtp;
  const int tid  = threadIdx.x;
  const int lane = tid & 63;
  const int w    = tid >> 6;          // wave 0..3
  const int c    = lane & 15;
  const int quad = lane >> 4;

  const int bh = blockIdx.x >> 5;
  const int q0 = (blockIdx.x & 31) * 64;

  __shared__ short ks[2][64 * 64];    // K tile [key][dim], swz: pos p row r holds
                                      //   global chunk p ^ (r&7) ^ (((r>>3)&1)<<2)
  __shared__ short vs[2][64 * 64];    // V^T tile [dim][key], swz: p ^ (r&7) (R8)

  // ---- Q B-fragments: lane n=c is q-row q0+w*16+c ----
  const float* qg = qp + ((size_t)(bh * S + q0 + w * 16 + c)) * D;
  short8 qB[2];
#pragma unroll
  for (int kk = 0; kk < 2; ++kk) {
    const float* p = qg + kk * 32 + quad * 8;
    float4 x = *(const float4*)(p);
    float4 y = *(const float4*)(p + 4);
    short8 f;
    f[0] = bf16rne(x.x * QSCALE); f[1] = bf16rne(x.y * QSCALE);
    f[2] = bf16rne(x.z * QSCALE); f[3] = bf16rne(x.w * QSCALE);
    f[4] = bf16rne(y.x * QSCALE); f[5] = bf16rne(y.y * QSCALE);
    f[6] = bf16rne(y.z * QSCALE); f[7] = bf16rne(y.w * QSCALE);
    qB[kk] = f;
  }

  f32x4 O[4];
#pragma unroll
  for (int t = 0; t < 4; ++t) O[t] = (f32x4){0.f, 0.f, 0.f, 0.f};
  f32x4 Lv = (f32x4){0.f, 0.f, 0.f, 0.f};   // 4 independent L chains (per-r)

  // staging geometry (R8): slot=(h2*4+w)*64+lane; row=(h2*4+w)*8+(lane>>3)
  const int rsub = lane >> 3;
  const int cswV = (lane & 7) ^ rsub;                 // V swizzle (R8)
  const int cswK = cswV ^ ((w & 1) << 2);             // K swizzle: row-bit3 spread (R17)
  const short* kbase = kb + ((size_t)(bh * S)) * D;
  const short* vbase = vt + ((size_t)(bh * D)) * S;

  const int sw0 = ((quad    ) ^ (c & 7)) * 8;         // V-read positions (R8)
  const int sw1 = ((quad | 4) ^ (c & 7)) * 8;
  const int kx  = (((c >> 2) & 1) << 2);              // K-read row-bit3 term

  const size_t mrow = ((size_t)(bh * S + q0 + w * 16 + c)) * S;

  unsigned long long mm0, mm1;        // mask prefetch: keys 8q..+7 / 32+8q..+7

  auto stage = [&](int it, int buf) {
    const int k0 = it * 64;
#pragma unroll
    for (int h2 = 0; h2 < 2; ++h2) {
      const int row = (h2 * 4 + w) * 8 + rsub;
      glds16(kbase + (size_t)(k0 + row) * 64 + cswK * 8,
             (char*)&ks[buf][0] + (h2 * 4 + w) * 1024);
      glds16(vbase + (size_t)row * S + k0 + cswV * 8,
             (char*)&vs[buf][0] + (h2 * 4 + w) * 1024);
    }
  };

  auto mload = [&](int it) {
    const int kO = it * 64;
    if (fmt == 1) {
      const unsigned char* mq = (const unsigned char*)mp + mrow + kO + 8 * quad;
      mm0 = __builtin_nontemporal_load((const unsigned long long*)mq);
      mm1 = __builtin_nontemporal_load((const unsigned long long*)(mq + 32));
    } else {
#pragma unroll
      for (int h = 0; h < 2; ++h) {
        const unsigned* m0 = (const unsigned*)mp + mrow + kO + h * 32 + 8 * quad;
        uintv4 a = __builtin_nontemporal_load((const uintv4*)m0);
        uintv4 b = __builtin_nontemporal_load((const uintv4*)(m0 + 4));
        unsigned long long t = 0ull;
#pragma unroll
        for (int j = 0; j < 4; ++j) {
          if (a[j]) t |= 0xffull << (8 * j);
          if (b[j]) t |= 0xffull << (8 * (j + 4));
        }
        if (h == 0) mm0 = t; else mm1 = t;
      }
    }
  };

  // ---- prologue ----
  stage(0, 0);
  mload(0);

  for (int it = 0; it < 32; ++it) {
    const int buf = it & 1;
    // ONE barrier/iter (R8): drains glds(it)+mask(it), orders prev-iter LDS reads
    // before the buf^1 writes issued next.
    __syncthreads();

    if (it + 1 < 32) stage(it + 1, buf ^ 1);

    const unsigned long long mb0 = mm0, mb1 = mm1;
    if (it + 1 < 32) mload(it + 1);

    // ---- compute cluster under raised priority (T5, R20-validated) ----
    __builtin_amdgcn_s_setprio(1);

    // scores, permuted A-rows; build PV A-fragments pa0/pa1 in registers (R17)
    // g: A-row m holds key 32*(g>=2) + 8*(m>>2) + 4*(g&1) + (m&3)
    //  => lane(quad,c) reg r = S^T[key 32*(g>=2)+8*quad+4*(g&1)+r][q=c]
    short8 pa0, pa1;
#pragma unroll
    for (int g = 0; g < 4; ++g) {
      const int r7 = (c & 3) + 4 * (g & 1);           // rr & 7
      const int rr = ((g & 2) << 4) + 8 * (c >> 2) + r7;
      const int px = ((quad ^ r7 ^ kx)) * 8;          // chunk pos for dims 8*quad..
      short8 ka0 = *(const short8*)&ks[buf][rr * 64 + px];
      short8 ka1 = *(const short8*)&ks[buf][rr * 64 + (px ^ 32)];  // dims 32+8*quad..
      f32x4 z = (f32x4){0.f, 0.f, 0.f, 0.f};
      z = __builtin_amdgcn_mfma_f32_16x16x32_bf16(ka0, qB[0], z, 0, 0, 0);
      z = __builtin_amdgcn_mfma_f32_16x16x32_bf16(ka1, qB[1], z, 0, 0, 0);
      const unsigned long long mq64 = (g & 2) ? mb1 : mb0;
      // u32 half for this g (bytes 4*(g&1)..+3): single-op v_bfe tests
      const unsigned mw = (g & 1) ? (unsigned)(mq64 >> 32) : (unsigned)mq64;
#pragma unroll
      for (int r = 0; r < 4; ++r) {
        const int j = 4 * (g & 1) + r;
        float e = ((mw >> (8 * r)) & 0xffu) ? 0.f : exp2f(z[r]);
        Lv[r] += e;                                    // 4 independent chains
        if (g & 2) pa1[j] = bf16rne(e); else pa0[j] = bf16rne(e);
      }
    }

    // O += P*V (pa register-direct; V reads = R8 pattern)
#pragma unroll
    for (int t = 0; t < 4; ++t) {
      short8 vb0 = *(const short8*)&vs[buf][(16 * t + c) * 64 + sw0];
      short8 vb1 = *(const short8*)&vs[buf][(16 * t + c) * 64 + sw1];
      O[t] = __builtin_amdgcn_mfma_f32_16x16x32_bf16(pa0, vb0, O[t], 0, 0, 0);
      O[t] = __builtin_amdgcn_mfma_f32_16x16x32_bf16(pa1, vb1, O[t], 0, 0, 0);
    }

    __builtin_amdgcn_s_setprio(0);
  }

  // ---- epilogue: single L reduction (deferred from loop), then O/L (R8) ----
  float Lt = (Lv[0] + Lv[1]) + (Lv[2] + Lv[3]);   // this lane's 16-key-per-iter sum
  Lt += __shfl_xor(Lt, 16);
  Lt += __shfl_xor(Lt, 32);                       // all lanes: full sum for q=c
#pragma unroll
  for (int r = 0; r < 4; ++r) {
    float Lr = __shfl(Lt, (lane & 48) | (quad * 4 + r));
    float inv = 1.f / Lr;
    const size_t ob = ((size_t)(bh * S + q0 + w * 16 + quad * 4 + r)) * D;
#pragma unroll
    for (int t = 0; t < 4; ++t) op[ob + 16 * t + c] = O[t][r] * inv;
  }
}

extern "C" void kernel_launch(void* const* d_in, const int* in_sizes, int n_in,
                              void* d_out, int out_size, void* d_ws, size_t ws_size,
                              hipStream_t stream) {
  const float* q = (const float*)d_in[0];
  const float* k = (const float*)d_in[1];
  const float* v = (const float*)d_in[2];
  const void*  m = d_in[3];

  short* kbuf = (short*)d_ws;                         // 8 MiB bf16 K
  short* vtb  = (short*)((char*)d_ws + (8u << 20));   // 8 MiB bf16 V^T
  int* flag   = (int*)((char*)d_ws + (16u << 20));

  prep<<<3072, 256, 0, stream>>>(k, v, kbuf, vtb, (const unsigned*)m, flag);
  attn_fwd<<<1024, 256, 0, stream>>>(q, kbuf, vtb, m, (float*)d_out, flag);
}